// Round 11
// baseline (3809.823 us; speedup 1.0000x reference)
//
#include <hip/hip_runtime.h>
#include <type_traits>

typedef _Float16 f16;
typedef _Float16 f16x4 __attribute__((ext_vector_type(4)));
typedef _Float16 f16x8 __attribute__((ext_vector_type(8)));
typedef float    f32x4 __attribute__((ext_vector_type(4)));

constexpr int TT = 512;   // timesteps
constexpr int FF = 64;    // input features
constexpr int H1 = 128;   // layer-1 hidden (512 gate cols)
constexpr int H2 = 64;    // layer-2 hidden (256 gate cols)
constexpr int D1 = 25;    // dense-1 width
constexpr int S1 = 136;   // h1 LDS row stride (f16)
constexpr int S2 = 72;    // h2 LDS row stride
constexpr int XC = 8;     // x timesteps per staged LDS chunk
constexpr float L2E = 1.44269504088896f;

// z pre-scaled by log2(e) at weight-load time: sigmoid = rcp(1 + 2^-z).
// (R20: trans ops are cheap on gfx950; keep the 3-op trans form.)
__device__ __forceinline__ float sigm2(float z) {
    return __builtin_amdgcn_rcpf(1.f + __builtin_amdgcn_exp2f(-z));
}

__device__ __forceinline__ f32x4 mfma16(f16x8 a, f16x8 b, f32x4 c) {
    return __builtin_amdgcn_mfma_f32_16x16x32_f16(a, b, c, 0, 0, 0);
}

__device__ __forceinline__ void gl_lds16(const f16* g, f16* l) {
    __builtin_amdgcn_global_load_lds(
        (const __attribute__((address_space(1))) unsigned int*)g,
        (__attribute__((address_space(3))) unsigned int*)l, 16, 0, 0);
}

// pre-pass: x fp32 -> f16 so staging is a raw byte copy.
__global__ void cvt_x_kernel(const float* __restrict__ x, f16* __restrict__ xh) {
    const size_t i = ((size_t)blockIdx.x * blockDim.x + threadIdx.x) * 4;
    const float4 v = *(const float4*)(x + i);
    f16x4 h; h[0] = (f16)v.x; h[1] = (f16)v.y; h[2] = (f16)v.z; h[3] = (f16)v.w;
    *(f16x4*)(xh + i) = h;
}

// R25: DUAL-TILE (A/B) restructure for wave-local MFMA||VALU overlap.
// Evidence: R19 (+143cy), R21 (prio: null), R22/R24 (fine SGB: null) -- the
// MFMA(1400cy) + VALU(1340cy) additivity survives every cross-wave
// scheduling lever. Matrix-pipe floor is 72 MFMA x 19.4cy = 1397 cy/step
// (~300us kernel); the gap is VALU that refuses to hide. New lever: each
// block owns TWO independent batch tiles (A: rows b0..b0+15, B: +16..31).
// Same weights serve both. Step body ping-pongs at source level so every
// sigma/tail block is adjacent to the OTHER tile's MFMA chain -- guaranteed
// independent work for in-order issue to overlap, no SGB (proven null,
// dropped). One barrier covers both tiles' steps (sync cost per unit work
// halves). Grid 16 x 768 threads; LDS ~101KB (1 block/CU; grid < #CU so
// occupancy unchanged in practice). Math per tile identical to R19/R14.
__global__ __launch_bounds__(768, 3)
void lstm_ab(const f16* __restrict__ xh, const float* __restrict__ W1,
             const float* __restrict__ U1, const float* __restrict__ b1,
             const float* __restrict__ W2, const float* __restrict__ U2,
             const float* __restrict__ b2, const float* __restrict__ Wd1,
             const float* __restrict__ bd1,const float* __restrict__ Wd2,
             const float* __restrict__ bd2, float* __restrict__ out)
{
    const int tid  = threadIdx.x;
    const int w    = tid >> 6;      // wave 0..11
    const int lane = tid & 63;
    const int quad = lane >> 4;
    const int lid  = lane & 15;
    const int b0   = blockIdx.x * 32;   // tile A: b0..b0+15, tile B: +16..+31
    const bool isL1 = (w < 8);
    const int  j    = isL1 ? w : (w - 8);

    __shared__ __align__(16) f16 h1bA[2][16][S1], h1bB[2][16][S1];
    __shared__ __align__(16) f16 h2bA[2][16][S2], h2bB[2][16][S2];
    // x chunk layout per tile: [tl(8)][fseg(8)][row(16)] of 16 B segments.
    __shared__ __align__(16) f16 xldsA[2][XC * 8 * 16 * 8];
    __shared__ __align__(16) f16 xldsB[2][XC * 8 * 16 * 8];
    __shared__ float h2fA[16][H2], h2fB[16][H2];
    __shared__ float dshA[16][D1], dshB[16][D1];

    for (int i = tid; i < 2 * 16 * S1 / 2; i += 768) {
        ((unsigned*)h1bA)[i] = 0u; ((unsigned*)h1bB)[i] = 0u;
    }
    for (int i = tid; i < 2 * 16 * S2 / 2; i += 768) {
        ((unsigned*)h2bA)[i] = 0u; ((unsigned*)h2bB)[i] = 0u;
    }

    // stage x chunk 0 for both tiles (s>>10 = tile, wave-uniform: 1024%64==0)
    for (int s = tid; s < 2 * XC * 8 * 16; s += 768) {
        const int tile = s >> 10, s2 = s & 1023;
        const int tl = s2 >> 7, fs = (s2 >> 4) & 7, row = s2 & 15;
        const f16* gp = xh + ((size_t)(b0 + tile * 16 + row) * TT + tl) * FF + fs * 8;
        f16* dst = (tile ? xldsB[0] : xldsA[0]) + (s2 >> 6) * 512;
        gl_lds16(gp, dst);
    }

    // ---- weight fragments wt[g][c] (A operand), shared by both tiles.
    // L1 (w<8):  chunks 0..3 = U1 (h1, K=128), 4..5 = W1 (x, K=64)
    // L2 (w>=8): chunks 0..3 = W2 (h1, K=128), 4..5 = U2 (h2, K=64)
    f16x8 wt[4][6];
    f32x4 bsp[4];
    float csA[4] = {0.f, 0.f, 0.f, 0.f};
    float csB[4] = {0.f, 0.f, 0.f, 0.f};

    if (isL1) {
#pragma unroll
        for (int g = 0; g < 4; ++g) {
            const float sc = (g == 2) ? 1.f : L2E;
            const int n = 128 * g + 16 * w + lid;
#pragma unroll
            for (int rr = 0; rr < 4; ++rr)
                bsp[g][rr] = b1[128 * g + 16 * w + quad * 4 + rr] * sc;
#pragma unroll
            for (int c = 0; c < 4; ++c) {
                f16x8 f;
#pragma unroll
                for (int e = 0; e < 8; ++e)
                    f[e] = (f16)(U1[(32 * c + quad * 8 + e) * 512 + n] * sc);
                wt[g][c] = f;
            }
#pragma unroll
            for (int c = 0; c < 2; ++c) {
                f16x8 f;
#pragma unroll
                for (int e = 0; e < 8; ++e)
                    f[e] = (f16)(W1[(32 * c + quad * 8 + e) * 512 + n] * sc);
                wt[g][4 + c] = f;
            }
        }
    } else {
#pragma unroll
        for (int g = 0; g < 4; ++g) {
            const float sc = (g == 2) ? 1.f : L2E;
            const int n = 64 * g + 16 * j + lid;
#pragma unroll
            for (int rr = 0; rr < 4; ++rr)
                bsp[g][rr] = b2[64 * g + 16 * j + quad * 4 + rr] * sc;
#pragma unroll
            for (int c = 0; c < 4; ++c) {
                f16x8 f;
#pragma unroll
                for (int e = 0; e < 8; ++e)
                    f[e] = (f16)(W2[(32 * c + quad * 8 + e) * 256 + n] * sc);
                wt[g][c] = f;
            }
#pragma unroll
            for (int c = 0; c < 2; ++c) {
                f16x8 f;
#pragma unroll
                for (int e = 0; e < 8; ++e)
                    f[e] = (f16)(U2[(32 * c + quad * 8 + e) * 256 + n] * sc);
                wt[g][4 + c] = f;
            }
        }
    }
    __syncthreads();   // also drains chunk-0 staging vmcnt

    if (isL1) asm volatile("s_setprio 1");

    // 6-MFMA gate chain helpers
    auto chain6 = [&](int g, f16x8 f0, f16x8 f1, f16x8 f2, f16x8 f3,
                      f16x8 f4, f16x8 f5) -> f32x4 {
        f32x4 a = mfma16(wt[g][0], f0, bsp[g]);
        a = mfma16(wt[g][1], f1, a);
        a = mfma16(wt[g][2], f2, a);
        a = mfma16(wt[g][3], f3, a);
        a = mfma16(wt[g][4], f4, a);
        a = mfma16(wt[g][5], f5, a);
        return a;
    };

    // one pipeline step, both tiles; PAR = i&1 compile-time.
    auto step = [&](auto parc, int i) {
        constexpr int PAR = decltype(parc)::value;
        constexpr int PR = PAR ^ 1;   // h1[i-1]
        constexpr int PW = PAR;       // h1[i]
        constexpr int QR = PAR;       // h2[i-2]
        constexpr int QW = PAR ^ 1;   // h2[i-1]
        if (isL1) {
            const f16* xcA = &xldsA[(i >> 3) & 1][(i & 7) * 1024];
            const f16* xcB = &xldsB[(i >> 3) & 1][(i & 7) * 1024];
            f16x8 fA0 = *(const f16x8*)&h1bA[PR][lid][quad * 8];
            f16x8 fA1 = *(const f16x8*)&h1bA[PR][lid][32 + quad * 8];
            f16x8 fA2 = *(const f16x8*)&h1bA[PR][lid][64 + quad * 8];
            f16x8 fA3 = *(const f16x8*)&h1bA[PR][lid][96 + quad * 8];
            f16x8 xA0 = *(const f16x8*)&xcA[(quad * 16 + lid) * 8];
            f16x8 xA1 = *(const f16x8*)&xcA[((4 + quad) * 16 + lid) * 8];
            f16x8 fB0 = *(const f16x8*)&h1bB[PR][lid][quad * 8];
            f16x8 fB1 = *(const f16x8*)&h1bB[PR][lid][32 + quad * 8];
            f16x8 fB2 = *(const f16x8*)&h1bB[PR][lid][64 + quad * 8];
            f16x8 fB3 = *(const f16x8*)&h1bB[PR][lid][96 + quad * 8];
            f16x8 xB0 = *(const f16x8*)&xcB[(quad * 16 + lid) * 8];
            f16x8 xB1 = *(const f16x8*)&xcB[((4 + quad) * 16 + lid) * 8];

            // ping-pong: every sigma block neighbors the OTHER tile's chain
            f32x4 aA0 = chain6(0, fA0, fA1, fA2, fA3, xA0, xA1);
            f32x4 aA1 = chain6(1, fA0, fA1, fA2, fA3, xA0, xA1);
            f32x4 aB0 = chain6(0, fB0, fB1, fB2, fB3, xB0, xB1);
            float igA[4];
#pragma unroll
            for (int r = 0; r < 4; ++r) igA[r] = sigm2(aA0[r]);
            f32x4 aB1 = chain6(1, fB0, fB1, fB2, fB3, xB0, xB1);
            float fgA[4];
#pragma unroll
            for (int r = 0; r < 4; ++r) fgA[r] = sigm2(aA1[r]);
            f32x4 aA2 = chain6(2, fA0, fA1, fA2, fA3, xA0, xA1);
            float igB[4];
#pragma unroll
            for (int r = 0; r < 4; ++r) igB[r] = sigm2(aB0[r]);
            f32x4 aA3 = chain6(3, fA0, fA1, fA2, fA3, xA0, xA1);
            float fgB[4];
#pragma unroll
            for (int r = 0; r < 4; ++r) fgB[r] = sigm2(aB1[r]);
            f32x4 aB2 = chain6(2, fB0, fB1, fB2, fB3, xB0, xB1);
            // tail A (overlaps aB2/aB3 chains)
            {
                f16x4 hp;
#pragma unroll
                for (int r = 0; r < 4; ++r) {
                    const float gg = fmaxf(aA2[r], 0.f);
                    const float og = sigm2(aA3[r]);
                    const float cc = fgA[r] * csA[r] + igA[r] * gg;
                    csA[r] = cc;
                    hp[r] = (f16)(og * fmaxf(cc, 0.f));
                }
                *(f16x4*)&h1bA[PW][lid][16 * w + quad * 4] = hp;
            }
            f32x4 aB3 = chain6(3, fB0, fB1, fB2, fB3, xB0, xB1);
            // tail B
            {
                f16x4 hp;
#pragma unroll
                for (int r = 0; r < 4; ++r) {
                    const float gg = fmaxf(aB2[r], 0.f);
                    const float og = sigm2(aB3[r]);
                    const float cc = fgB[r] * csB[r] + igB[r] * gg;
                    csB[r] = cc;
                    hp[r] = (f16)(og * fmaxf(cc, 0.f));
                }
                *(f16x4*)&h1bB[PW][lid][16 * w + quad * 4] = hp;
            }
        } else {
            if (i >= 1) {
                f16x8 fA0 = *(const f16x8*)&h1bA[PR][lid][quad * 8];
                f16x8 fA1 = *(const f16x8*)&h1bA[PR][lid][32 + quad * 8];
                f16x8 fA2 = *(const f16x8*)&h1bA[PR][lid][64 + quad * 8];
                f16x8 fA3 = *(const f16x8*)&h1bA[PR][lid][96 + quad * 8];
                f16x8 fA4 = *(const f16x8*)&h2bA[QR][lid][quad * 8];
                f16x8 fA5 = *(const f16x8*)&h2bA[QR][lid][32 + quad * 8];
                f16x8 fB0 = *(const f16x8*)&h1bB[PR][lid][quad * 8];
                f16x8 fB1 = *(const f16x8*)&h1bB[PR][lid][32 + quad * 8];
                f16x8 fB2 = *(const f16x8*)&h1bB[PR][lid][64 + quad * 8];
                f16x8 fB3 = *(const f16x8*)&h1bB[PR][lid][96 + quad * 8];
                f16x8 fB4 = *(const f16x8*)&h2bB[QR][lid][quad * 8];
                f16x8 fB5 = *(const f16x8*)&h2bB[QR][lid][32 + quad * 8];

                f32x4 aA0 = chain6(0, fA0, fA1, fA2, fA3, fA4, fA5);
                f32x4 aA1 = chain6(1, fA0, fA1, fA2, fA3, fA4, fA5);
                f32x4 aB0 = chain6(0, fB0, fB1, fB2, fB3, fB4, fB5);
                float igA[4];
#pragma unroll
                for (int r = 0; r < 4; ++r) igA[r] = sigm2(aA0[r]);
                f32x4 aB1 = chain6(1, fB0, fB1, fB2, fB3, fB4, fB5);
                float fgA[4];
#pragma unroll
                for (int r = 0; r < 4; ++r) fgA[r] = sigm2(aA1[r]);
                f32x4 aA2 = chain6(2, fA0, fA1, fA2, fA3, fA4, fA5);
                float igB[4];
#pragma unroll
                for (int r = 0; r < 4; ++r) igB[r] = sigm2(aB0[r]);
                f32x4 aA3 = chain6(3, fA0, fA1, fA2, fA3, fA4, fA5);
                float fgB[4];
#pragma unroll
                for (int r = 0; r < 4; ++r) fgB[r] = sigm2(aB1[r]);
                f32x4 aB2 = chain6(2, fB0, fB1, fB2, fB3, fB4, fB5);
                {
                    f16x4 hp;
#pragma unroll
                    for (int r = 0; r < 4; ++r) {
                        const float gg = fmaxf(aA2[r], 0.f);
                        const float og = sigm2(aA3[r]);
                        const float cc = fgA[r] * csA[r] + igA[r] * gg;
                        csA[r] = cc;
                        hp[r] = (f16)(og * fmaxf(cc, 0.f));
                    }
                    *(f16x4*)&h2bA[QW][lid][16 * j + quad * 4] = hp;
                }
                f32x4 aB3 = chain6(3, fB0, fB1, fB2, fB3, fB4, fB5);
                {
                    f16x4 hp;
#pragma unroll
                    for (int r = 0; r < 4; ++r) {
                        const float gg = fmaxf(aB2[r], 0.f);
                        const float og = sigm2(aB3[r]);
                        const float cc = fgB[r] * csB[r] + igB[r] * gg;
                        csB[r] = cc;
                        hp[r] = (f16)(og * fmaxf(cc, 0.f));
                    }
                    *(f16x4*)&h2bB[QW][lid][16 * j + quad * 4] = hp;
                }
            }
        }
    };

    // ---------------- main loop, unrolled x2: ONE barrier per step ----------------
    for (int ii = 0; ii < TT; ii += 2) {
        if ((ii & (XC - 1)) == 0 && ii + XC < TT) {
            const int nc = (ii >> 3) + 1;
            f16* dA = xldsA[nc & 1];
            f16* dB = xldsB[nc & 1];
            for (int s = tid; s < 2 * XC * 8 * 16; s += 768) {
                const int tile = s >> 10, s2 = s & 1023;
                const int tl = s2 >> 7, fs = (s2 >> 4) & 7, row = s2 & 15;
                const f16* gp = xh + ((size_t)(b0 + tile * 16 + row) * TT + (nc * XC + tl)) * FF + fs * 8;
                gl_lds16(gp, (tile ? dB : dA) + (s2 >> 6) * 512);
            }
        }
        step(std::integral_constant<int, 0>{}, ii);
        __syncthreads();
        step(std::integral_constant<int, 1>{}, ii + 1);
        __syncthreads();
    }

    if (isL1) asm volatile("s_setprio 0");

    // final pipeline step i=TT (even): L2 consumes h1[TT-1], exports h2 f32
    if (!isL1) {
#pragma unroll
        for (int t = 0; t < 2; ++t) {
            const f16 (*h1p)[16][S1] = t ? h1bB : h1bA;
            const f16 (*h2p)[16][S2] = t ? h2bB : h2bA;
            float* cs = t ? csB : csA;
            f16x8 f0 = *(const f16x8*)&h1p[1][lid][quad * 8];
            f16x8 f1 = *(const f16x8*)&h1p[1][lid][32 + quad * 8];
            f16x8 f2 = *(const f16x8*)&h1p[1][lid][64 + quad * 8];
            f16x8 f3 = *(const f16x8*)&h1p[1][lid][96 + quad * 8];
            f16x8 f4 = *(const f16x8*)&h2p[0][lid][quad * 8];
            f16x8 f5 = *(const f16x8*)&h2p[0][lid][32 + quad * 8];
            f32x4 acc[4];
#pragma unroll
            for (int g = 0; g < 4; ++g) acc[g] = chain6(g, f0, f1, f2, f3, f4, f5);
            float4 ho;
#pragma unroll
            for (int r = 0; r < 4; ++r) {
                const float ig = sigm2(acc[0][r]);
                const float fg = sigm2(acc[1][r]);
                const float gg = fmaxf(acc[2][r], 0.f);
                const float og = sigm2(acc[3][r]);
                const float cc = fg * cs[r] + ig * gg;
                (&ho.x)[r] = og * fmaxf(cc, 0.f);
            }
            if (t) *(float4*)&h2fB[lid][16 * j + quad * 4] = ho;
            else   *(float4*)&h2fA[lid][16 * j + quad * 4] = ho;
        }
    }
    __syncthreads();

    // ---------------- dense head (both tiles) ----------------
    for (int idx = tid; idx < 16 * D1; idx += 768) {
        const int bq = idx / D1, p = idx % D1;
        float dA = bd1[p], dB = bd1[p];
#pragma unroll
        for (int k = 0; k < H2; ++k) {
            dA += h2fA[bq][k] * Wd1[k * D1 + p];
            dB += h2fB[bq][k] * Wd1[k * D1 + p];
        }
        dshA[bq][p] = dA * Wd2[p];
        dshB[bq][p] = dB * Wd2[p];
    }
    __syncthreads();
    if (tid < 32) {
        const int tile = tid >> 4, r = tid & 15;
        float o = bd2[0];
#pragma unroll
        for (int p = 0; p < D1; ++p) o += (tile ? dshB[r][p] : dshA[r][p]);
        out[b0 + tile * 16 + r] = o;
    }
}

extern "C" void kernel_launch(void* const* d_in, const int* in_sizes, int n_in,
                              void* d_out, int out_size, void* d_ws, size_t ws_size,
                              hipStream_t stream) {
    (void)in_sizes; (void)n_in; (void)out_size; (void)ws_size;
    const float* x   = (const float*)d_in[0];
    const float* W1  = (const float*)d_in[1];
    const float* U1  = (const float*)d_in[2];
    const float* b1  = (const float*)d_in[3];
    const float* W2  = (const float*)d_in[4];
    const float* U2  = (const float*)d_in[5];
    const float* b2  = (const float*)d_in[6];
    const float* Wd1 = (const float*)d_in[7];
    const float* bd1 = (const float*)d_in[8];
    const float* Wd2 = (const float*)d_in[9];
    const float* bd2 = (const float*)d_in[10];
    float* out = (float*)d_out;
    f16*   xh  = (f16*)d_ws;    // 512*512*64 f16 = 32 MiB scratch

    const int nx = 512 * 512 * 64;
    cvt_x_kernel<<<dim3(nx / (256 * 4)), dim3(256), 0, stream>>>(x, xh);
    lstm_ab<<<dim3(16), dim3(768), 0, stream>>>(
        xh, W1, U1, b1, W2, U2, b2, Wd1, bd1, Wd2, bd2, out);
}